// Round 4
// baseline (2799.086 us; speedup 1.0000x reference)
//
#include <hip/hip_runtime.h>

#define N_USERS   100000
#define N_ITEMS   50000
#define N_NODES   150000
#define EMBED_DIM 128
#define N_EDGES   6400000
#define USER_FLOATS (N_USERS * EMBED_DIM)   // 12,800,000
#define TOTAL_FLOATS (N_NODES * EMBED_DIM)  // 19,200,000
#define NB_SCAN   586                        // ceil(150000/256)
#define BKT_SHIFT 7
#define NBKT      1172                       // ceil(150000/128)

// fp32 -> bf16 round-to-nearest-even (returns low 16 bits)
static __device__ __forceinline__ unsigned bf16_rne(float f) {
    unsigned u = __float_as_uint(f);
    return (u + 0x7fffu + ((u >> 16) & 1u)) >> 16;
}

// ---------------- CSR build ----------------

__global__ __launch_bounds__(256) void hist_kernel(const int* __restrict__ edge_dst,
                                                   int* __restrict__ counts) {
    int e = blockIdx.x * 256 + threadIdx.x;
    if (e < N_EDGES) atomicAdd(&counts[edge_dst[e]], 1);
}

__global__ __launch_bounds__(256) void scan1_kernel(const int* __restrict__ counts,
                                                    int* __restrict__ row_ptr,
                                                    int* __restrict__ bsum) {
    __shared__ int tmp[256];
    int i = blockIdx.x * 256 + threadIdx.x;
    int v = (i < N_NODES) ? counts[i] : 0;
    tmp[threadIdx.x] = v;
    __syncthreads();
    for (int off = 1; off < 256; off <<= 1) {
        int t = (threadIdx.x >= off) ? tmp[threadIdx.x - off] : 0;
        __syncthreads();
        tmp[threadIdx.x] += t;
        __syncthreads();
    }
    int incl = tmp[threadIdx.x];
    if (i < N_NODES) row_ptr[i] = incl - v;       // exclusive local
    if (threadIdx.x == 255) bsum[blockIdx.x] = incl;
}

__global__ __launch_bounds__(1024) void scan2_kernel(int* __restrict__ bsum) {
    __shared__ int tmp[1024];
    int t = threadIdx.x;
    int v = (t < NB_SCAN) ? bsum[t] : 0;
    tmp[t] = v;
    __syncthreads();
    for (int off = 1; off < 1024; off <<= 1) {
        int x = (t >= off) ? tmp[t - off] : 0;
        __syncthreads();
        tmp[t] += x;
        __syncthreads();
    }
    if (t < NB_SCAN) bsum[t] = tmp[t] - v;        // exclusive
}

__global__ __launch_bounds__(256) void scan3_kernel(int* __restrict__ row_ptr,
                                                    const int* __restrict__ bsum) {
    int i = blockIdx.x * 256 + threadIdx.x;
    if (i < N_NODES) row_ptr[i] += bsum[blockIdx.x];
    if (i == 0) row_ptr[N_NODES] = N_EDGES;
}

// Pass 1: bin edges by dst>>7. Per-bucket writes are SEQUENTIAL (cursor), so
// cache lines fill completely instead of one 8B touch per line.
// record: x = src | (dst&127)<<18 (src<2^18), y = bits of w
__global__ __launch_bounds__(256) void bin_kernel(const int* __restrict__ edge_src,
                                                  const int* __restrict__ edge_dst,
                                                  const float* __restrict__ edge_vals,
                                                  const int* __restrict__ row_ptr,
                                                  int* __restrict__ bcur,
                                                  int2* __restrict__ bin) {
    int e = blockIdx.x * 256 + threadIdx.x;
    if (e >= N_EDGES) return;
    int dst = edge_dst[e];
    int b = dst >> BKT_SHIFT;
    int base = row_ptr[b << BKT_SHIFT];          // bucket region base in CSR space
    int pos = atomicAdd(&bcur[b], 1);
    int2 r;
    r.x = edge_src[e] | ((dst & 127) << 18);
    r.y = __float_as_int(edge_vals[e]);
    bin[base + pos] = r;
}

// Pass 2: one workgroup per bucket; sequential read of the bucket's records,
// scatter within the bucket's ~44KB CSR window (L2-resident, written fully
// and exclusively by this workgroup -> full-line evictions).
__global__ __launch_bounds__(256) void local_scatter_kernel(const int* __restrict__ row_ptr,
                                                            const int2* __restrict__ bin,
                                                            int* __restrict__ cursor,
                                                            int2* __restrict__ cw) {
    int b = blockIdx.x;
    int node0 = b << BKT_SHIFT;
    int node1 = node0 + 128; if (node1 > N_NODES) node1 = N_NODES;
    int lo = row_ptr[node0];
    int hi = row_ptr[node1];
    for (int i = lo + (int)threadIdx.x; i < hi; i += 256) {
        int2 r = bin[i];
        int dst = node0 + (r.x >> 18);
        int src = r.x & 0x3FFFF;
        int slot = row_ptr[dst] + atomicAdd(&cursor[dst], 1);
        int2 o; o.x = src; o.y = r.y;
        cw[slot] = o;
    }
}

// ---------------- init: cur(bf16) = all_emb, acc(out, fp32) = 0.25*all_emb ----------------

__global__ __launch_bounds__(256) void init_kernel(const float4* __restrict__ user_w,
                                                   const float4* __restrict__ item_w,
                                                   uint2* __restrict__ cur,
                                                   float4* __restrict__ acc) {
    int i = blockIdx.x * 256 + threadIdx.x;              // float4 index
    if (i >= TOTAL_FLOATS / 4) return;
    float4 v;
    if (i < USER_FLOATS / 4) v = user_w[i];
    else                     v = item_w[i - USER_FLOATS / 4];
    uint2 c;
    c.x = bf16_rne(v.x) | (bf16_rne(v.y) << 16);
    c.y = bf16_rne(v.z) | (bf16_rne(v.w) << 16);
    cur[i] = c;
    float4 a;
    a.x = 0.25f * v.x; a.y = 0.25f * v.y; a.z = 0.25f * v.z; a.w = 0.25f * v.w;
    acc[i] = a;
}

// ---------------- SpMM: next(bf16) = A*cur(bf16) ; acc(fp32) += 0.25*next ----------------
// One wave per node. Quarter-wave (16 lanes x 16B = 8 bf16 dims/lane) covers the
// 128-dim row; the 4 quarters process 4 different source rows per iteration,
// combined by shfl_xor(16)+shfl_xor(32).

__global__ __launch_bounds__(256) void spmm_kernel(const int* __restrict__ row_ptr,
                                                   const int2* __restrict__ cw,
                                                   const uint4* __restrict__ cur,
                                                   uint4* __restrict__ next,
                                                   float4* __restrict__ acc,
                                                   int write_next) {
    int wid  = (blockIdx.x * 256 + threadIdx.x) >> 6;    // node id
    int lane = threadIdx.x & 63;
    int q    = lane >> 4;                                // quarter 0..3
    int l    = lane & 15;                                // uint4 index in row
    if (wid >= N_NODES) return;
    int start = row_ptr[wid];
    int end   = row_ptr[wid + 1];
    float s[8];
    #pragma unroll
    for (int c = 0; c < 8; ++c) s[c] = 0.f;
    for (int base = start; base < end; base += 64) {
        int n = end - base;
        if (n > 64) n = 64;
        int idx = base + (lane < n ? lane : n - 1);
        int2 p = cw[idx];
        float cwf = (lane < n) ? __int_as_float(p.y) : 0.f;
        int m = (n + 3) >> 2;
        for (int j = 0; j < m; ++j) {
            int k = 4 * j + q;                           // this quarter's source
            int   src = __shfl(p.x, k);
            float vw  = __shfl(cwf, k);                  // 0 for padded tail
            uint4 v = cur[src * 16 + l];
            s[0] += vw * __uint_as_float(v.x << 16);
            s[1] += vw * __uint_as_float(v.x & 0xffff0000u);
            s[2] += vw * __uint_as_float(v.y << 16);
            s[3] += vw * __uint_as_float(v.y & 0xffff0000u);
            s[4] += vw * __uint_as_float(v.z << 16);
            s[5] += vw * __uint_as_float(v.z & 0xffff0000u);
            s[6] += vw * __uint_as_float(v.w << 16);
            s[7] += vw * __uint_as_float(v.w & 0xffff0000u);
        }
    }
    #pragma unroll
    for (int c = 0; c < 8; ++c) {
        s[c] += __shfl_xor(s[c], 16);
        s[c] += __shfl_xor(s[c], 32);
    }
    if (q == 0) {
        if (write_next) {
            uint4 o;
            o.x = bf16_rne(s[0]) | (bf16_rne(s[1]) << 16);
            o.y = bf16_rne(s[2]) | (bf16_rne(s[3]) << 16);
            o.z = bf16_rne(s[4]) | (bf16_rne(s[5]) << 16);
            o.w = bf16_rne(s[6]) | (bf16_rne(s[7]) << 16);
            next[wid * 16 + l] = o;
        }
    } else if (q == 1) {
        int o = wid * 32 + 2 * l;
        float4 a = acc[o];
        a.x += 0.25f * s[0]; a.y += 0.25f * s[1];
        a.z += 0.25f * s[2]; a.w += 0.25f * s[3];
        acc[o] = a;
        float4 b = acc[o + 1];
        b.x += 0.25f * s[4]; b.y += 0.25f * s[5];
        b.z += 0.25f * s[6]; b.w += 0.25f * s[7];
        acc[o + 1] = b;
    }
}

// ---------------- launch ----------------

extern "C" void kernel_launch(void* const* d_in, const int* in_sizes, int n_in,
                              void* d_out, int out_size, void* d_ws, size_t ws_size,
                              hipStream_t stream) {
    const int*   edge_src  = (const int*)  d_in[0];
    const int*   edge_dst  = (const int*)  d_in[1];
    const float* edge_vals = (const float*)d_in[2];
    const float* user_w    = (const float*)d_in[3];
    const float* item_w    = (const float*)d_in[4];
    float* out = (float*)d_out;

    // workspace layout (bytes)
    char* ws = (char*)d_ws;
    unsigned* cur = (unsigned*)(ws);                     // bf16: 38,400,000 B
    unsigned* nxt = (unsigned*)(ws + 38400000);          // bf16: 38,400,000 B
    int* row_ptr  = (int*)    (ws + 76800000);           // 600,064 B (150001 ints)
    int* bsum     = (int*)    (ws + 77400064);           // 4,096 B
    int* cursor   = (int*)    (ws + 77404160);           // 600,000 B (also counts)
    int* bcur     = (int*)    (ws + 78004160);           // 8,192 B (1172 used)
    int2* bin     = (int2*)   (ws + 78012352);           // 51,200,000 B
    int2* cw      = (int2*)   (ws + 129212352);          // 51,200,000 B
    // total: 180,412,352 B

    const int EB = (N_EDGES + 255) / 256;       // 25000
    const int IB = (TOTAL_FLOATS / 4 + 255) / 256;
    const int SB = (N_NODES * 64 + 255) / 256;  // 37500

    // --- CSR build ---
    hipMemsetAsync(cursor, 0, N_NODES * sizeof(int), stream);   // counts
    hist_kernel<<<EB, 256, 0, stream>>>(edge_dst, cursor);
    scan1_kernel<<<NB_SCAN, 256, 0, stream>>>(cursor, row_ptr, bsum);
    scan2_kernel<<<1, 1024, 0, stream>>>(bsum);
    scan3_kernel<<<NB_SCAN, 256, 0, stream>>>(row_ptr, bsum);
    hipMemsetAsync(bcur, 0, NBKT * sizeof(int), stream);
    bin_kernel<<<EB, 256, 0, stream>>>(edge_src, edge_dst, edge_vals,
                                       row_ptr, bcur, bin);
    hipMemsetAsync(cursor, 0, N_NODES * sizeof(int), stream);
    local_scatter_kernel<<<NBKT, 256, 0, stream>>>(row_ptr, bin, cursor, cw);

    // --- init ---
    init_kernel<<<IB, 256, 0, stream>>>((const float4*)user_w, (const float4*)item_w,
                                        (uint2*)cur, (float4*)out);

    // --- 3 propagation layers ---
    unsigned* a = cur;
    unsigned* b = nxt;
    for (int layer = 0; layer < 3; ++layer) {
        spmm_kernel<<<SB, 256, 0, stream>>>(row_ptr, cw,
                                            (const uint4*)a, (uint4*)b, (float4*)out,
                                            layer < 2 ? 1 : 0);
        unsigned* t = a; a = b; b = t;
    }
}

// Round 5
// 971.117 us; speedup vs baseline: 2.8823x; 2.8823x over previous
//
#include <hip/hip_runtime.h>

#define N_USERS   100000
#define N_ITEMS   50000
#define N_NODES   150000
#define EMBED_DIM 128
#define N_EDGES   6400000
#define USER_FLOATS (N_USERS * EMBED_DIM)   // 12,800,000
#define TOTAL_FLOATS (N_NODES * EMBED_DIM)  // 19,200,000
#define BKT_SHIFT 8
#define BKT_SIZE  256
#define NBKT      586                        // ceil(150000/256)
#define NCHUNK    256
#define CHUNK_SZ  25000                      // 6,400,000 / 256
#define CMAT_N    (NBKT * NCHUNK)            // 150,016 (= 256*586 exactly)
#define CMAT_BLOCKS 586

// fp32 -> bf16 round-to-nearest-even (returns low 16 bits)
static __device__ __forceinline__ unsigned bf16_rne(float f) {
    unsigned u = __float_as_uint(f);
    return (u + 0x7fffu + ((u >> 16) & 1u)) >> 16;
}

// ---------------- generic scan (3-kernel) ----------------

__global__ __launch_bounds__(256) void scan1_kernel(const int* __restrict__ in,
                                                    int* __restrict__ out,
                                                    int* __restrict__ bsum, int n) {
    __shared__ int tmp[256];
    int i = blockIdx.x * 256 + threadIdx.x;
    int v = (i < n) ? in[i] : 0;
    tmp[threadIdx.x] = v;
    __syncthreads();
    for (int off = 1; off < 256; off <<= 1) {
        int t = (threadIdx.x >= off) ? tmp[threadIdx.x - off] : 0;
        __syncthreads();
        tmp[threadIdx.x] += t;
        __syncthreads();
    }
    int incl = tmp[threadIdx.x];
    if (i < n) out[i] = incl - v;                 // exclusive local
    if (threadIdx.x == 255) bsum[blockIdx.x] = incl;
}

// single block, 1024 threads, handles nb <= 2048 (2 elems/thread)
__global__ __launch_bounds__(1024) void scan2_kernel(int* __restrict__ bsum, int nb) {
    __shared__ int tmp[1024];
    int t = threadIdx.x;
    int v0 = (2 * t     < nb) ? bsum[2 * t]     : 0;
    int v1 = (2 * t + 1 < nb) ? bsum[2 * t + 1] : 0;
    tmp[t] = v0 + v1;
    __syncthreads();
    for (int off = 1; off < 1024; off <<= 1) {
        int x = (t >= off) ? tmp[t - off] : 0;
        __syncthreads();
        tmp[t] += x;
        __syncthreads();
    }
    int base = (t > 0) ? tmp[t - 1] : 0;          // exclusive pair base
    if (2 * t     < nb) bsum[2 * t]     = base;
    if (2 * t + 1 < nb) bsum[2 * t + 1] = base + v0;
}

__global__ __launch_bounds__(256) void scan3_kernel(int* __restrict__ out,
                                                    const int* __restrict__ bsum,
                                                    int n, int tail_val) {
    int i = blockIdx.x * 256 + threadIdx.x;
    if (i < n) out[i] += bsum[blockIdx.x];
    if (i == 0) out[n] = tail_val;                // sentinel
}

// ---------------- two-level binning (no global atomics) ----------------

// Per-chunk LDS histogram over dst>>8 buckets -> cmat[bucket][chunk]
__global__ __launch_bounds__(512) void chunk_hist_kernel(const int* __restrict__ edge_dst,
                                                         int* __restrict__ cmat) {
    __shared__ int h[NBKT];
    int wg = blockIdx.x;
    for (int b = threadIdx.x; b < NBKT; b += 512) h[b] = 0;
    __syncthreads();
    int e0 = wg * CHUNK_SZ, e1 = e0 + CHUNK_SZ;
    for (int e = e0 + (int)threadIdx.x; e < e1; e += 512)
        atomicAdd(&h[edge_dst[e] >> BKT_SHIFT], 1);
    __syncthreads();
    for (int b = threadIdx.x; b < NBKT; b += 512) cmat[b * NCHUNK + wg] = h[b];
}

// Place records at exact positions: LDS cursors seeded from the scanned coff.
// record: x = src | (dst&255)<<18 (src < 2^18), y = bits of w
__global__ __launch_bounds__(512) void bin_place_kernel(const int* __restrict__ edge_src,
                                                        const int* __restrict__ edge_dst,
                                                        const float* __restrict__ edge_vals,
                                                        const int* __restrict__ coff,
                                                        int2* __restrict__ bin) {
    __shared__ int cur[NBKT];
    int wg = blockIdx.x;
    for (int b = threadIdx.x; b < NBKT; b += 512) cur[b] = coff[b * NCHUNK + wg];
    __syncthreads();
    int e0 = wg * CHUNK_SZ, e1 = e0 + CHUNK_SZ;
    for (int e = e0 + (int)threadIdx.x; e < e1; e += 512) {
        int dst = edge_dst[e];
        int b = dst >> BKT_SHIFT;
        int pos = atomicAdd(&cur[b], 1);         // LDS atomic only
        int2 r;
        r.x = edge_src[e] | ((dst & 255) << 18);
        r.y = __float_as_int(edge_vals[e]);
        bin[pos] = r;
    }
}

// One wg per bucket: per-node LDS hist + LDS scan -> row_ptr slice, then
// scatter within the bucket's ~87KB L2-resident window (LDS cursors only).
__global__ __launch_bounds__(256) void local_scatter_kernel(const int* __restrict__ coff,
                                                            const int2* __restrict__ bin,
                                                            int* __restrict__ row_ptr,
                                                            int2* __restrict__ cw) {
    __shared__ int hist[BKT_SIZE];
    __shared__ int curs[BKT_SIZE];
    int b = blockIdx.x;
    int t = threadIdx.x;
    int node0 = b << BKT_SHIFT;
    int lo = coff[b * NCHUNK];
    int hi = coff[(b + 1) * NCHUNK];
    hist[t] = 0;
    __syncthreads();
    for (int i = lo + t; i < hi; i += 256)
        atomicAdd(&hist[bin[i].x >> 18], 1);
    __syncthreads();
    int v = hist[t];
    curs[t] = v;
    __syncthreads();
    for (int off = 1; off < 256; off <<= 1) {
        int x = (t >= off) ? curs[t - off] : 0;
        __syncthreads();
        curs[t] += x;
        __syncthreads();
    }
    int excl = curs[t] - v;
    __syncthreads();
    curs[t] = excl;                               // becomes within-bucket cursor
    int node = node0 + t;
    if (node < N_NODES) row_ptr[node] = lo + excl;
    if (b == 0 && t == 0) row_ptr[N_NODES] = N_EDGES;
    __syncthreads();
    for (int i = lo + t; i < hi; i += 256) {
        int2 r = bin[i];
        int dl  = r.x >> 18;
        int src = r.x & 0x3FFFF;
        int slot = lo + atomicAdd(&curs[dl], 1);  // LDS atomic only
        int2 o; o.x = src; o.y = r.y;
        cw[slot] = o;
    }
}

// ---------------- init: cur(bf16) = all_emb, acc(out, fp32) = 0.25*all_emb ----------------

__global__ __launch_bounds__(256) void init_kernel(const float4* __restrict__ user_w,
                                                   const float4* __restrict__ item_w,
                                                   uint2* __restrict__ cur,
                                                   float4* __restrict__ acc) {
    int i = blockIdx.x * 256 + threadIdx.x;              // float4 index
    if (i >= TOTAL_FLOATS / 4) return;
    float4 v;
    if (i < USER_FLOATS / 4) v = user_w[i];
    else                     v = item_w[i - USER_FLOATS / 4];
    uint2 c;
    c.x = bf16_rne(v.x) | (bf16_rne(v.y) << 16);
    c.y = bf16_rne(v.z) | (bf16_rne(v.w) << 16);
    cur[i] = c;
    float4 a;
    a.x = 0.25f * v.x; a.y = 0.25f * v.y; a.z = 0.25f * v.z; a.w = 0.25f * v.w;
    acc[i] = a;
}

// ---------------- SpMM: next(bf16) = A*cur(bf16) ; acc(fp32) += 0.25*next ----------------
// One wave per node. Quarter-wave (16 lanes x 16B = 8 bf16 dims/lane) covers the
// 128-dim row; the 4 quarters process 4 different source rows per iteration,
// combined by shfl_xor(16)+shfl_xor(32).

__global__ __launch_bounds__(256) void spmm_kernel(const int* __restrict__ row_ptr,
                                                   const int2* __restrict__ cw,
                                                   const uint4* __restrict__ cur,
                                                   uint4* __restrict__ next,
                                                   float4* __restrict__ acc,
                                                   int write_next) {
    int wid  = (blockIdx.x * 256 + threadIdx.x) >> 6;    // node id
    int lane = threadIdx.x & 63;
    int q    = lane >> 4;                                // quarter 0..3
    int l    = lane & 15;                                // uint4 index in row
    if (wid >= N_NODES) return;
    int start = row_ptr[wid];
    int end   = row_ptr[wid + 1];
    float s[8];
    #pragma unroll
    for (int c = 0; c < 8; ++c) s[c] = 0.f;
    for (int base = start; base < end; base += 64) {
        int n = end - base;
        if (n > 64) n = 64;
        int idx = base + (lane < n ? lane : n - 1);
        int2 p = cw[idx];
        float cwf = (lane < n) ? __int_as_float(p.y) : 0.f;
        int m = (n + 3) >> 2;
        for (int j = 0; j < m; ++j) {
            int k = 4 * j + q;                           // this quarter's source
            int   src = __shfl(p.x, k);
            float vw  = __shfl(cwf, k);                  // 0 for padded tail
            uint4 v = cur[src * 16 + l];
            s[0] += vw * __uint_as_float(v.x << 16);
            s[1] += vw * __uint_as_float(v.x & 0xffff0000u);
            s[2] += vw * __uint_as_float(v.y << 16);
            s[3] += vw * __uint_as_float(v.y & 0xffff0000u);
            s[4] += vw * __uint_as_float(v.z << 16);
            s[5] += vw * __uint_as_float(v.z & 0xffff0000u);
            s[6] += vw * __uint_as_float(v.w << 16);
            s[7] += vw * __uint_as_float(v.w & 0xffff0000u);
        }
    }
    #pragma unroll
    for (int c = 0; c < 8; ++c) {
        s[c] += __shfl_xor(s[c], 16);
        s[c] += __shfl_xor(s[c], 32);
    }
    if (q == 0) {
        if (write_next) {
            uint4 o;
            o.x = bf16_rne(s[0]) | (bf16_rne(s[1]) << 16);
            o.y = bf16_rne(s[2]) | (bf16_rne(s[3]) << 16);
            o.z = bf16_rne(s[4]) | (bf16_rne(s[5]) << 16);
            o.w = bf16_rne(s[6]) | (bf16_rne(s[7]) << 16);
            next[wid * 16 + l] = o;
        }
    } else if (q == 1) {
        int o = wid * 32 + 2 * l;
        float4 a = acc[o];
        a.x += 0.25f * s[0]; a.y += 0.25f * s[1];
        a.z += 0.25f * s[2]; a.w += 0.25f * s[3];
        acc[o] = a;
        float4 b = acc[o + 1];
        b.x += 0.25f * s[4]; b.y += 0.25f * s[5];
        b.z += 0.25f * s[6]; b.w += 0.25f * s[7];
        acc[o + 1] = b;
    }
}

// ---------------- launch ----------------

extern "C" void kernel_launch(void* const* d_in, const int* in_sizes, int n_in,
                              void* d_out, int out_size, void* d_ws, size_t ws_size,
                              hipStream_t stream) {
    const int*   edge_src  = (const int*)  d_in[0];
    const int*   edge_dst  = (const int*)  d_in[1];
    const float* edge_vals = (const float*)d_in[2];
    const float* user_w    = (const float*)d_in[3];
    const float* item_w    = (const float*)d_in[4];
    float* out = (float*)d_out;

    // workspace layout (bytes)
    char* ws = (char*)d_ws;
    unsigned* cur = (unsigned*)(ws);                     // bf16: 38,400,000 B
    unsigned* nxt = (unsigned*)(ws + 38400000);          // bf16: 38,400,000 B
    int*  row_ptr = (int*)    (ws + 76800000);           // 600,064 B (150,001 ints)
    int*  cmat    = (int*)    (ws + 77400064);           // 600,064 B (150,016 ints)
    int*  coff    = (int*)    (ws + 78000128);           // 600,128 B (150,017 ints)
    int*  bsum    = (int*)    (ws + 78600256);           // 8,192 B
    int2* bin     = (int2*)   (ws + 78608448);           // 51,200,000 B
    int2* cw      = (int2*)   (ws + 129808448);          // 51,200,000 B
    // total: 181,008,448 B

    const int IB = (TOTAL_FLOATS / 4 + 255) / 256;
    const int SB = (N_NODES * 64 + 255) / 256;  // 37500

    // --- CSR build (no global atomics anywhere) ---
    chunk_hist_kernel<<<NCHUNK, 512, 0, stream>>>(edge_dst, cmat);
    scan1_kernel<<<CMAT_BLOCKS, 256, 0, stream>>>(cmat, coff, bsum, CMAT_N);
    scan2_kernel<<<1, 1024, 0, stream>>>(bsum, CMAT_BLOCKS);
    scan3_kernel<<<CMAT_BLOCKS, 256, 0, stream>>>(coff, bsum, CMAT_N, N_EDGES);
    bin_place_kernel<<<NCHUNK, 512, 0, stream>>>(edge_src, edge_dst, edge_vals,
                                                 coff, bin);
    local_scatter_kernel<<<NBKT, 256, 0, stream>>>(coff, bin, row_ptr, cw);

    // --- init ---
    init_kernel<<<IB, 256, 0, stream>>>((const float4*)user_w, (const float4*)item_w,
                                        (uint2*)cur, (float4*)out);

    // --- 3 propagation layers ---
    unsigned* a = cur;
    unsigned* b = nxt;
    for (int layer = 0; layer < 3; ++layer) {
        spmm_kernel<<<SB, 256, 0, stream>>>(row_ptr, cw,
                                            (const uint4*)a, (uint4*)b, (float4*)out,
                                            layer < 2 ? 1 : 0);
        unsigned* t = a; a = b; b = t;
    }
}